// Round 18
// baseline (148.307 us; speedup 1.0000x reference)
//
#include <hip/hip_runtime.h>
#include <hip/hip_bf16.h>

// SoftmaxAggr: h = relu(x @ W^T + b); alpha = segment_softmax(h*t); out = segment_sum(h*alpha)
// |h*t| small -> skip max-subtraction:
//   out[g][c] = sum_{i in g} h*exp(h*t) / (sum_{i in g} exp(h*t) + 1e-16)
// R18 = R17 (120us best) + epilogue software-pipelined by ONE TILE: tile n's
// epilogue (VALU: fma/exp/shfl + 2 stores) executes inside tile n+1's body,
// in the same scheduling region as the K-loop (after LOAD8+sched_barrier,
// before the fence) -> compiler can interleave epilogue VALU into the K-loop's
// lgkmcnt stall slots (different pipes: VALU vs LDS/MFMA). Dual named acc sets
// accE/accO (rule #20); pending epilogue peeled after the loop via parity.
// All in-loop waits remain compiler-emitted (session law).

typedef __attribute__((ext_vector_type(8))) short short8;
typedef __attribute__((ext_vector_type(4))) float f32x4;
typedef __attribute__((ext_vector_type(4))) unsigned u32x4;
typedef __attribute__((ext_vector_type(2))) unsigned u32x2;

#define D_INN 256
#define HID 256
#define BM 64            // rows per tile = 64 KB fp32 -> 34 KB bf16 (padded) in LDS
#define NGRID 256        // persistent blocks, 1 per CU
#define NTHREADS 512     // 8 waves, each owns 32 channels
#define PSB 544          // padded LDS row stride bytes (272 shorts): conflict-free

__device__ __forceinline__ unsigned pk2(float a, float b) {
    unsigned r;
    asm("v_cvt_pk_bf16_f32 %0, %1, %2" : "=v"(r) : "v"(a), "v"(b));
    return r;   // [15:0]=bf16(a), [31:16]=bf16(b)  (RNE)
}

__global__ void zero_sp(float* __restrict__ sp) {
    int i = blockIdx.x * blockDim.x + threadIdx.x;
    ((f32x4*)sp)[i] = (f32x4){0.f, 0.f, 0.f, 0.f};
}

__global__ void finalize(const float* __restrict__ S, const float* __restrict__ P,
                         float* __restrict__ out) {
    int i = blockIdx.x * blockDim.x + threadIdx.x;
    out[i] = P[i] / (S[i] + 1e-16f);
}

// MODE 0: plain-store partials; MODE 1: atomic fallback (part=S, P=P)
template<int MODE>
__global__ __launch_bounds__(NTHREADS, 2) void gemm_fused(
    const float* __restrict__ x, const int* __restrict__ gidx,
    const float* __restrict__ W, const float* __restrict__ bias,
    const float* __restrict__ temp, float* __restrict__ part, float* __restrict__ P,
    int NT)
{
    __shared__ __align__(16) short Alds[2][BM * (PSB / 2)];   // 2 x 34 KB bf16 (padded)
    __shared__ uint4 Mlds[32];

    const int t = threadIdx.x;
    const int w = t >> 6;          // wave 0..7: channels [w*32, w*32+32)
    const int l = t & 63;
    const int lrow = l & 15;
    const int lq = l >> 4;
    const int blk = blockIdx.x;

    // ---- prologue meta: wave w computes tiles it = w, w+8, w+16, w+24 ----
#pragma unroll
    for (int k = 0; k < 4; ++k) {
        const int it = w + k * 8;
        const int tile = blk + it * NGRID;
        if (tile < NT) {
            const int sid = gidx[(size_t)tile * BM + l];
            const int s0 = __shfl(sid, 0);
            const int s63 = __shfl(sid, 63);
            const unsigned long long m = __ballot(sid != s0);
            if (l == 0)
                Mlds[it] = make_uint4((unsigned)s0, (unsigned)s63,
                                      (unsigned)m, (unsigned)(m >> 32));
        }
    }

    // ---- W fp32 -> bf16 VGPRs: 16 x short8 = 64 VGPRs ----
    short8 bvAll[2][8];
#pragma unroll
    for (int ni = 0; ni < 2; ++ni)
#pragma unroll
        for (int ks = 0; ks < 8; ++ks) {
            const float* wp = W + (size_t)(w * 32 + ni * 16 + lrow) * D_INN + ks * 32 + lq * 8;
            float4 a = ((const float4*)wp)[0];
            float4 b = ((const float4*)wp)[1];
            u32x4 ua;
            ua.x = pk2(a.x, a.y); ua.y = pk2(a.z, a.w);
            ua.z = pk2(b.x, b.y); ua.w = pk2(b.z, b.w);
            bvAll[ni][ks] = __builtin_bit_cast(short8, ua);
        }
    float bb[2], tt[2];
#pragma unroll
    for (int ni = 0; ni < 2; ++ni) {
        bb[ni] = bias[w * 32 + ni * 16 + lrow];
        tt[ni] = temp[w * 32 + ni * 16 + lrow];
    }

    // staging map: thread t handles float4 #(r*512+t), r=0..7 (wave reads 1KB/instr)
    //   elem = (r*512+t)*4 -> row = r*8+w, col = l*4  -> LDS byte = row*PSB + l*8
    char* const wr0 = (char*)&Alds[0][0] + (w * PSB) + l * 8;   // + r*8*PSB
    char* const wr1 = (char*)&Alds[1][0] + (w * PSB) + l * 8;
    // MFMA A-frag read: row = mi*16+lrow, k-bytes = ks*64 + lq*16 (affine, padded)
    const int rb = lrow * PSB + lq * 16;                        // + mi*16*PSB + ks*64

    float4 ra[8], rbuf[8];
    f32x4 accE[4][2], accO[4][2];

#define LOAD8(dst, tile)                                                        \
    {                                                                           \
        const float4* xp = (const float4*)(x + (size_t)(tile) * (BM * D_INN)) + t; \
        _Pragma("unroll")                                                       \
        for (int r = 0; r < 8; ++r) dst[r] = xp[r * 512];                       \
    }

#define CVTW(src, wrbase)                                                       \
    {                                                                           \
        _Pragma("unroll")                                                       \
        for (int r = 0; r < 8; ++r) {                                           \
            u32x2 p;                                                            \
            p.x = pk2(src[r].x, src[r].y);                                      \
            p.y = pk2(src[r].z, src[r].w);                                      \
            *(u32x2*)(wrbase + r * 8 * PSB) = p;                                \
        }                                                                       \
    }

#define KLOOP(bufidx, accv)                                                     \
    {                                                                           \
        _Pragma("unroll")                                                       \
        for (int i = 0; i < 4; ++i)                                             \
            _Pragma("unroll")                                                   \
            for (int j = 0; j < 2; ++j) accv[i][j] = (f32x4){0.f, 0.f, 0.f, 0.f};\
        const char* lb = (const char*)&Alds[bufidx][0] + rb;                    \
        _Pragma("unroll")                                                       \
        for (int ks = 0; ks < 8; ++ks) {                                        \
            short8 av[4];                                                       \
            _Pragma("unroll")                                                   \
            for (int mi = 0; mi < 4; ++mi)                                      \
                av[mi] = *(const short8*)(lb + mi * 16 * PSB + ks * 64);        \
            _Pragma("unroll")                                                   \
            for (int mi = 0; mi < 4; ++mi)                                      \
                _Pragma("unroll")                                               \
                for (int ni = 0; ni < 2; ++ni)                                  \
                    accv[mi][ni] = __builtin_amdgcn_mfma_f32_16x16x32_bf16(     \
                        av[mi], bvAll[ni][ks], accv[mi][ni], 0, 0, 0);          \
        }                                                                       \
    }

#define EPILOGUE(accv, itv, jtv)                                                \
    {                                                                           \
        const uint4 mt = Mlds[itv];                                             \
        const int s0 = (int)mt.x, s63 = (int)mt.y;                              \
        float* pb = part + ((size_t)(jtv) << 10);                               \
        int himask = 0;                                                         \
        _Pragma("unroll")                                                       \
        for (int mi = 0; mi < 4; ++mi) {                                        \
            const unsigned mk = (mi < 2) ? mt.z : mt.w;                         \
            const int base = (mi & 1) * 16 + lq * 4;                            \
            _Pragma("unroll")                                                   \
            for (int j = 0; j < 4; ++j)                                         \
                if ((mk >> (base + j)) & 1) himask |= 1 << (mi * 4 + j);        \
        }                                                                       \
        _Pragma("unroll")                                                       \
        for (int ni = 0; ni < 2; ++ni) {                                        \
            float es0 = 0.f, ps0 = 0.f, es1 = 0.f, ps1 = 0.f;                   \
            _Pragma("unroll")                                                   \
            for (int mi = 0; mi < 4; ++mi)                                      \
                _Pragma("unroll")                                               \
                for (int j = 0; j < 4; ++j) {                                   \
                    float h = fmaxf(accv[mi][ni][j] + bb[ni], 0.f);             \
                    float e = __expf(h * tt[ni]);                               \
                    if ((himask >> (mi * 4 + j)) & 1) { es1 += e; ps1 += h * e; }\
                    else                              { es0 += e; ps0 += h * e; }\
                }                                                               \
            es0 += __shfl_xor(es0, 16); ps0 += __shfl_xor(ps0, 16);             \
            es0 += __shfl_xor(es0, 32); ps0 += __shfl_xor(ps0, 32);             \
            es1 += __shfl_xor(es1, 16); ps1 += __shfl_xor(ps1, 16);             \
            es1 += __shfl_xor(es1, 32); ps1 += __shfl_xor(ps1, 32);             \
            if (l < 16) {                                                       \
                const int ch = w * 32 + ni * 16 + lrow;                         \
                if (MODE == 1) {                                                \
                    atomicAdd(&part[(size_t)s0 * HID + ch], es0);               \
                    atomicAdd(&P[(size_t)s0 * HID + ch], ps0);                  \
                    atomicAdd(&part[(size_t)s63 * HID + ch], es1);              \
                    atomicAdd(&P[(size_t)s63 * HID + ch], ps1);                 \
                } else {                                                        \
                    f32x4 v; v.x = es0; v.y = ps0; v.z = es1; v.w = ps1;        \
                    *(f32x4*)&pb[4 * ch] = v;                                   \
                }                                                               \
            }                                                                   \
        }                                                                       \
    }

#define FENCE_BARRIER()                                          \
    asm volatile("s_waitcnt lgkmcnt(0)" ::: "memory");           \
    __builtin_amdgcn_s_barrier();                                \
    __builtin_amdgcn_sched_barrier(0);

    // ---- prologue: tile0 -> ra -> LDS0; tile1 -> rbuf (in flight) ----
    LOAD8(ra, blk);
    LOAD8(rbuf, blk + NGRID);          // NT=6250 > 2*NGRID always here
    __builtin_amdgcn_sched_barrier(0);
    CVTW(ra, wr0);                     // compiler waits ra's loads only
    FENCE_BARRIER();                   // also publishes Mlds

    // ---- peeled tile 0 (even, no pending epilogue) ----
    {
        LOAD8(ra, blk + 2 * NGRID);    // 767 < 6250 always
        __builtin_amdgcn_sched_barrier(0);
        KLOOP(0, accE);
        if (blk + NGRID < NT) {
            CVTW(rbuf, wr1);
            FENCE_BARRIER();
        }
    }

    for (int it = 1;; it += 2) {
        // ---- odd body: epilogue(accE, tile it-1); compute LDS1 -> accO ----
        {
            const int n = blk + it * NGRID;
            if (n >= NT) break;
            const int tgt = n + 2 * NGRID;
            if (tgt < NT) LOAD8(rbuf, tgt);
            __builtin_amdgcn_sched_barrier(0);
            EPILOGUE(accE, it - 1, n - NGRID);
            KLOOP(1, accO);
            if (n + NGRID < NT) {
                CVTW(ra, wr0);
                FENCE_BARRIER();
            }
        }
        // ---- even body: epilogue(accO, tile it); compute LDS0 -> accE ----
        {
            const int n2 = blk + (it + 1) * NGRID;
            if (n2 >= NT) break;
            const int tgt2 = n2 + 2 * NGRID;
            if (tgt2 < NT) LOAD8(ra, tgt2);
            __builtin_amdgcn_sched_barrier(0);
            EPILOGUE(accO, it, n2 - NGRID);
            KLOOP(0, accE);
            if (n2 + NGRID < NT) {
                CVTW(rbuf, wr1);
                FENCE_BARRIER();
            }
        }
    }

    // ---- tail: one pending epilogue (last computed tile) ----
    {
        const int lastIt = (NT - 1 - blk) / NGRID;
        const int lastJt = blk + lastIt * NGRID;
        if (lastIt & 1) { EPILOGUE(accO, lastIt, lastJt); }
        else            { EPILOGUE(accE, lastIt, lastJt); }
    }
#undef LOAD8
#undef CVTW
#undef KLOOP
#undef EPILOGUE
#undef FENCE_BARRIER
}

// one block per segment; thread = channel; binary-search tile range in sorted gidx
__global__ void reduce_seg(const int* __restrict__ gidx, const float* __restrict__ part,
                           float* __restrict__ out, int N) {
    const int g = blockIdx.x;
    const int ch = threadIdx.x;
    int lo = 0, hi = N;
    while (lo < hi) { int m = (lo + hi) >> 1; if (gidx[m] < g) lo = m + 1; else hi = m; }
    const int r0 = lo;
    hi = N;
    while (lo < hi) { int m = (lo + hi) >> 1; if (gidx[m] < g + 1) lo = m + 1; else hi = m; }
    const int r1 = lo;
    float es = 0.f, ps = 0.f;
    if (r0 < r1) {
        const int b0 = r0 >> 6, b1 = (r1 - 1) >> 6;   // BM = 64
        for (int b = b0; b <= b1; ++b) {
            const f32x4* pb = (const f32x4*)(part + ((size_t)b << 10));
            f32x4 v = pb[ch];
            if (gidx[b << 6] == g) { es += v.x; ps += v.y; }   // tile starts in g
            else                   { es += v.z; ps += v.w; }   // tail rows from prev seg
        }
    }
    out[(size_t)g * HID + ch] = ps / (es + 1e-16f);
}

extern "C" void kernel_launch(void* const* d_in, const int* in_sizes, int n_in,
                              void* d_out, int out_size, void* d_ws, size_t ws_size,
                              hipStream_t stream) {
    const float* x    = (const float*)d_in[0];
    const int*   gidx = (const int*)d_in[1];
    const float* W    = (const float*)d_in[3];
    const float* bias = (const float*)d_in[4];
    const float* temp = (const float*)d_in[5];
    float* out = (float*)d_out;

    const int N = in_sizes[1];        // 400000
    const int B = out_size / HID;     // 1024
    const int NT = N / BM;            // 6250 tiles

    const size_t partFloats = (size_t)NT * 1024;
    const size_t need = partFloats * 4;

    if (ws_size >= need) {
        float* part = (float*)d_ws;
        gemm_fused<0><<<NGRID, NTHREADS, 0, stream>>>(x, gidx, W, bias, temp, part, nullptr, NT);
        reduce_seg<<<B, 256, 0, stream>>>(gidx, part, out, N);
    } else {
        float* S = (float*)d_ws;
        float* P = S + (size_t)B * HID;
        zero_sp<<<(2 * B * HID) / (256 * 4), 256, 0, stream>>>(S);
        gemm_fused<1><<<NGRID, NTHREADS, 0, stream>>>(x, gidx, W, bias, temp, S, P, NT);
        finalize<<<(B * HID) / 256, 256, 0, stream>>>(S, P, out);
    }
}

// Round 19
// 135.229 us; speedup vs baseline: 1.0967x; 1.0967x over previous
//
#include <hip/hip_runtime.h>
#include <hip/hip_bf16.h>

// SoftmaxAggr: h = relu(x @ W^T + b); alpha = segment_softmax(h*t); out = segment_sum(h*alpha)
// |h*t| small -> skip max-subtraction:
//   out[g][c] = sum_{i in g} h*exp(h*t) / (sum_{i in g} exp(h*t) + 1e-16)
// R19 = R17 (120us best) with FOUR LDS buffers and ONE fence per TWO tiles:
//   body s: CVTW ra->bufC, rb->bufD (fence s-1 proved C,D readers done);
//           LOAD8 ra,rb (tiles +4,+5: 2-tile latency cover);
//           compute+epi tile 2s (bufA); compute+epi tile 2s+1 (bufB); FENCE.
// Laws respected: CVTW ds_writes once at region top (not per-ks, R15 lesson);
// epilogue shfl after its K-loop (R18 lesson); loads before stores; all in-loop
// waits compiler-emitted (R5/R16 lesson). Fences/block: 25 -> 13.

typedef __attribute__((ext_vector_type(8))) short short8;
typedef __attribute__((ext_vector_type(4))) float f32x4;
typedef __attribute__((ext_vector_type(4))) unsigned u32x4;
typedef __attribute__((ext_vector_type(2))) unsigned u32x2;

#define D_INN 256
#define HID 256
#define BM 64            // rows per tile = 64 KB fp32 -> 34 KB bf16 (padded) in LDS
#define NGRID 256        // persistent blocks, 1 per CU
#define NTHREADS 512     // 8 waves, each owns 32 channels
#define PSB 544          // padded LDS row stride bytes (272 shorts): conflict-free
#define BUFSH (BM * (PSB / 2))   // shorts per buffer

__device__ __forceinline__ unsigned pk2(float a, float b) {
    unsigned r;
    asm("v_cvt_pk_bf16_f32 %0, %1, %2" : "=v"(r) : "v"(a), "v"(b));
    return r;   // [15:0]=bf16(a), [31:16]=bf16(b)  (RNE)
}

__global__ void zero_sp(float* __restrict__ sp) {
    int i = blockIdx.x * blockDim.x + threadIdx.x;
    ((f32x4*)sp)[i] = (f32x4){0.f, 0.f, 0.f, 0.f};
}

__global__ void finalize(const float* __restrict__ S, const float* __restrict__ P,
                         float* __restrict__ out) {
    int i = blockIdx.x * blockDim.x + threadIdx.x;
    out[i] = P[i] / (S[i] + 1e-16f);
}

// MODE 0: plain-store partials; MODE 1: atomic fallback (part=S, P=P)
template<int MODE>
__global__ __launch_bounds__(NTHREADS, 2) void gemm_fused(
    const float* __restrict__ x, const int* __restrict__ gidx,
    const float* __restrict__ W, const float* __restrict__ bias,
    const float* __restrict__ temp, float* __restrict__ part, float* __restrict__ P,
    int NT)
{
    __shared__ __align__(16) short Alds[4][BUFSH];   // 4 x 34 KB bf16 (padded)
    __shared__ uint4 Mlds[32];

    const int t = threadIdx.x;
    const int w = t >> 6;          // wave 0..7: channels [w*32, w*32+32)
    const int l = t & 63;
    const int lrow = l & 15;
    const int lq = l >> 4;
    const int blk = blockIdx.x;

    // ---- prologue meta: wave w computes tiles it = w, w+8, w+16, w+24 ----
#pragma unroll
    for (int k = 0; k < 4; ++k) {
        const int it = w + k * 8;
        const int tile = blk + it * NGRID;
        if (tile < NT) {
            const int sid = gidx[(size_t)tile * BM + l];
            const int s0 = __shfl(sid, 0);
            const int s63 = __shfl(sid, 63);
            const unsigned long long m = __ballot(sid != s0);
            if (l == 0)
                Mlds[it] = make_uint4((unsigned)s0, (unsigned)s63,
                                      (unsigned)m, (unsigned)(m >> 32));
        }
    }

    // ---- W fp32 -> bf16 VGPRs: 16 x short8 = 64 VGPRs ----
    short8 bvAll[2][8];
#pragma unroll
    for (int ni = 0; ni < 2; ++ni)
#pragma unroll
        for (int ks = 0; ks < 8; ++ks) {
            const float* wp = W + (size_t)(w * 32 + ni * 16 + lrow) * D_INN + ks * 32 + lq * 8;
            float4 a = ((const float4*)wp)[0];
            float4 b = ((const float4*)wp)[1];
            u32x4 ua;
            ua.x = pk2(a.x, a.y); ua.y = pk2(a.z, a.w);
            ua.z = pk2(b.x, b.y); ua.w = pk2(b.z, b.w);
            bvAll[ni][ks] = __builtin_bit_cast(short8, ua);
        }
    float bb[2], tt[2];
#pragma unroll
    for (int ni = 0; ni < 2; ++ni) {
        bb[ni] = bias[w * 32 + ni * 16 + lrow];
        tt[ni] = temp[w * 32 + ni * 16 + lrow];
    }

    // staging map: thread t handles float4 #(r*512+t), r=0..7
    //   elem = (r*512+t)*4 -> row = r*8+w, col = l*4  -> LDS byte = row*PSB + l*8
    const int wroff = w * PSB + l * 8;                 // + r*8*PSB, + buf*BUFSH*2
    const int rb = lrow * PSB + lq * 16;               // + mi*16*PSB + ks*64

    float4 ra[8], rbuf[8];

#define LOAD8(dst, tile)                                                        \
    {                                                                           \
        const float4* xp = (const float4*)(x + (size_t)(tile) * (BM * D_INN)) + t; \
        _Pragma("unroll")                                                       \
        for (int r = 0; r < 8; ++r) dst[r] = xp[r * 512];                       \
    }

#define CVTW(src, bufi)                                                         \
    {                                                                           \
        char* wrbase = (char*)&Alds[bufi][0] + wroff;                           \
        _Pragma("unroll")                                                       \
        for (int r = 0; r < 8; ++r) {                                           \
            u32x2 p;                                                            \
            p.x = pk2(src[r].x, src[r].y);                                      \
            p.y = pk2(src[r].z, src[r].w);                                      \
            *(u32x2*)(wrbase + r * 8 * PSB) = p;                                \
        }                                                                       \
    }

#define COMPUTE_STORE(bufidx, it, jt)                                           \
    {                                                                           \
        const uint4 mt = Mlds[it];                                              \
        f32x4 acc[4][2];                                                        \
        _Pragma("unroll")                                                       \
        for (int i = 0; i < 4; ++i)                                             \
            _Pragma("unroll")                                                   \
            for (int j = 0; j < 2; ++j) acc[i][j] = (f32x4){0.f, 0.f, 0.f, 0.f};\
        const char* lb = (const char*)&Alds[bufidx][0] + rb;                    \
        _Pragma("unroll")                                                       \
        for (int ks = 0; ks < 8; ++ks) {                                        \
            short8 av[4];                                                       \
            _Pragma("unroll")                                                   \
            for (int mi = 0; mi < 4; ++mi)                                      \
                av[mi] = *(const short8*)(lb + mi * 16 * PSB + ks * 64);        \
            _Pragma("unroll")                                                   \
            for (int mi = 0; mi < 4; ++mi)                                      \
                _Pragma("unroll")                                               \
                for (int ni = 0; ni < 2; ++ni)                                  \
                    acc[mi][ni] = __builtin_amdgcn_mfma_f32_16x16x32_bf16(      \
                        av[mi], bvAll[ni][ks], acc[mi][ni], 0, 0, 0);           \
        }                                                                       \
        const int s0 = (int)mt.x, s63 = (int)mt.y;                              \
        float* pb = part + ((size_t)(jt) << 10);                                \
        int himask = 0;                                                         \
        _Pragma("unroll")                                                       \
        for (int mi = 0; mi < 4; ++mi) {                                        \
            const unsigned mk = (mi < 2) ? mt.z : mt.w;                         \
            const int base = (mi & 1) * 16 + lq * 4;                            \
            _Pragma("unroll")                                                   \
            for (int j = 0; j < 4; ++j)                                         \
                if ((mk >> (base + j)) & 1) himask |= 1 << (mi * 4 + j);        \
        }                                                                       \
        _Pragma("unroll")                                                       \
        for (int ni = 0; ni < 2; ++ni) {                                        \
            float es0 = 0.f, ps0 = 0.f, es1 = 0.f, ps1 = 0.f;                   \
            _Pragma("unroll")                                                   \
            for (int mi = 0; mi < 4; ++mi)                                      \
                _Pragma("unroll")                                               \
                for (int j = 0; j < 4; ++j) {                                   \
                    float h = fmaxf(acc[mi][ni][j] + bb[ni], 0.f);              \
                    float e = __expf(h * tt[ni]);                               \
                    if ((himask >> (mi * 4 + j)) & 1) { es1 += e; ps1 += h * e; }\
                    else                              { es0 += e; ps0 += h * e; }\
                }                                                               \
            es0 += __shfl_xor(es0, 16); ps0 += __shfl_xor(ps0, 16);             \
            es0 += __shfl_xor(es0, 32); ps0 += __shfl_xor(ps0, 32);             \
            es1 += __shfl_xor(es1, 16); ps1 += __shfl_xor(ps1, 16);             \
            es1 += __shfl_xor(es1, 32); ps1 += __shfl_xor(ps1, 32);             \
            if (l < 16) {                                                       \
                const int ch = w * 32 + ni * 16 + lrow;                         \
                if (MODE == 1) {                                                \
                    atomicAdd(&part[(size_t)s0 * HID + ch], es0);               \
                    atomicAdd(&P[(size_t)s0 * HID + ch], ps0);                  \
                    atomicAdd(&part[(size_t)s63 * HID + ch], es1);              \
                    atomicAdd(&P[(size_t)s63 * HID + ch], ps1);                 \
                } else {                                                        \
                    f32x4 v; v.x = es0; v.y = ps0; v.z = es1; v.w = ps1;        \
                    *(f32x4*)&pb[4 * ch] = v;                                   \
                }                                                               \
            }                                                                   \
        }                                                                       \
    }

#define FENCE_BARRIER()                                          \
    asm volatile("s_waitcnt lgkmcnt(0)" ::: "memory");           \
    __builtin_amdgcn_s_barrier();                                \
    __builtin_amdgcn_sched_barrier(0);

// body for super-iter SV: tiles 2*SV (buf BA), 2*SV+1 (buf BB); cvtw -> BC, BD
#define BODY(SV, BA, BB, BC, BD)                                                \
    {                                                                           \
        const int n0 = blk + (2 * (SV)) * NGRID;                                \
        if (n0 >= NT) goto done;                                                \
        const int n1 = n0 + NGRID;                                              \
        if (n1 < NT) {                                                          \
            if (n0 + 2 * NGRID < NT) { CVTW(ra, BC); }                          \
            if (n1 + 2 * NGRID < NT) { CVTW(rbuf, BD); }                        \
            if (n0 + 4 * NGRID < NT) { LOAD8(ra, n0 + 4 * NGRID); }             \
            if (n1 + 4 * NGRID < NT) { LOAD8(rbuf, n1 + 4 * NGRID); }           \
            __builtin_amdgcn_sched_barrier(0);                                  \
            COMPUTE_STORE(BA, 2 * (SV), n0);                                    \
            COMPUTE_STORE(BB, 2 * (SV) + 1, n1);                                \
            if (n0 + 2 * NGRID < NT) { FENCE_BARRIER(); }                       \
        } else {                                                                \
            COMPUTE_STORE(BA, 2 * (SV), n0);                                    \
            goto done;                                                          \
        }                                                                       \
    }

    // ---- prologue: t0,t1 -> regs -> buf0,buf1; t2,t3 -> regs (in flight) ----
    LOAD8(ra, blk);
    LOAD8(rbuf, blk + NGRID);
    __builtin_amdgcn_sched_barrier(0);
    CVTW(ra, 0);
    CVTW(rbuf, 1);
    LOAD8(ra, blk + 2 * NGRID);        // t2 (always exists: 767 < 6250)
    LOAD8(rbuf, blk + 3 * NGRID);      // t3
    FENCE_BARRIER();                   // publishes buf0,buf1 + Mlds

    for (int s = 0;; s += 2) {
        BODY(s, 0, 1, 2, 3);
        BODY(s + 1, 2, 3, 0, 1);
    }
done: ;
#undef LOAD8
#undef CVTW
#undef COMPUTE_STORE
#undef FENCE_BARRIER
#undef BODY
}

// one block per segment; thread = channel; binary-search tile range in sorted gidx
__global__ void reduce_seg(const int* __restrict__ gidx, const float* __restrict__ part,
                           float* __restrict__ out, int N) {
    const int g = blockIdx.x;
    const int ch = threadIdx.x;
    int lo = 0, hi = N;
    while (lo < hi) { int m = (lo + hi) >> 1; if (gidx[m] < g) lo = m + 1; else hi = m; }
    const int r0 = lo;
    hi = N;
    while (lo < hi) { int m = (lo + hi) >> 1; if (gidx[m] < g + 1) lo = m + 1; else hi = m; }
    const int r1 = lo;
    float es = 0.f, ps = 0.f;
    if (r0 < r1) {
        const int b0 = r0 >> 6, b1 = (r1 - 1) >> 6;   // BM = 64
        for (int b = b0; b <= b1; ++b) {
            const f32x4* pb = (const f32x4*)(part + ((size_t)b << 10));
            f32x4 v = pb[ch];
            if (gidx[b << 6] == g) { es += v.x; ps += v.y; }   // tile starts in g
            else                   { es += v.z; ps += v.w; }   // tail rows from prev seg
        }
    }
    out[(size_t)g * HID + ch] = ps / (es + 1e-16f);
}

extern "C" void kernel_launch(void* const* d_in, const int* in_sizes, int n_in,
                              void* d_out, int out_size, void* d_ws, size_t ws_size,
                              hipStream_t stream) {
    const float* x    = (const float*)d_in[0];
    const int*   gidx = (const int*)d_in[1];
    const float* W    = (const float*)d_in[3];
    const float* bias = (const float*)d_in[4];
    const float* temp = (const float*)d_in[5];
    float* out = (float*)d_out;

    const int N = in_sizes[1];        // 400000
    const int B = out_size / HID;     // 1024
    const int NT = N / BM;            // 6250 tiles

    const size_t partFloats = (size_t)NT * 1024;
    const size_t need = partFloats * 4;

    if (ws_size >= need) {
        float* part = (float*)d_ws;
        gemm_fused<0><<<NGRID, NTHREADS, 0, stream>>>(x, gidx, W, bias, temp, part, nullptr, NT);
        reduce_seg<<<B, 256, 0, stream>>>(gidx, part, out, N);
    } else {
        float* S = (float*)d_ws;
        float* P = S + (size_t)B * HID;
        zero_sp<<<(2 * B * HID) / (256 * 4), 256, 0, stream>>>(S);
        gemm_fused<1><<<NGRID, NTHREADS, 0, stream>>>(x, gidx, W, bias, temp, S, P, NT);
        finalize<<<(B * HID) / 256, 256, 0, stream>>>(S, P, out);
    }
}

// Round 20
// 129.860 us; speedup vs baseline: 1.1421x; 1.0413x over previous
//
#include <hip/hip_runtime.h>
#include <hip/hip_bf16.h>

// SoftmaxAggr: h = relu(x @ W^T + b); alpha = segment_softmax(h*t); out = segment_sum(h*alpha)
// |h*t| small -> skip max-subtraction:
//   out[g][c] = sum_{i in g} h*exp(h*t) / (sum_{i in g} exp(h*t) + 1e-16)
// R20 = R17 (120us best) with BM=128: halves fence count (25->13/block) and all
// per-tile fixed costs, PRESERVING R17's exact ordering law (LOAD -> SB ->
// COMPUTE -> CVTW -> FENCE; CVTW compute-covered at tail; all waits
// compiler-emitted). ra/rbuf = the two HALVES of the next tile (not two tiles):
//   body n: LOAD8H(ra, n+1, h2); SB; COMPUTE(tile n, acc[8][2]);
//           CVTW(rbuf->buf^1 h1)[old]; CVTW(ra->buf^1 h2)[covered];
//           LOAD8H(rbuf, n+2, h1); FENCE.
// VGPR ~215 (bvAll 64 + acc 64 + ra/rbuf 64); LDS 2x68KB=136KB; Mlds[16][2]
// (128-bit boundary mask). R18/R19 lessons: no shfl before K-loop, no ds_write
// at body top, nothing VMEM-tracked entering the queue out of order.

typedef __attribute__((ext_vector_type(8))) short short8;
typedef __attribute__((ext_vector_type(4))) float f32x4;
typedef __attribute__((ext_vector_type(4))) unsigned u32x4;
typedef __attribute__((ext_vector_type(2))) unsigned u32x2;

#define D_INN 256
#define HID 256
#define BM 128           // rows per tile = 128 KB fp32 -> 68 KB bf16 (padded) in LDS
#define NGRID 256        // persistent blocks, 1 per CU
#define NTHREADS 512     // 8 waves, each owns 32 channels
#define PSB 544          // padded LDS row stride bytes (272 shorts): conflict-free
#define BUFSH (BM * (PSB / 2))

__device__ __forceinline__ unsigned pk2(float a, float b) {
    unsigned r;
    asm("v_cvt_pk_bf16_f32 %0, %1, %2" : "=v"(r) : "v"(a), "v"(b));
    return r;   // [15:0]=bf16(a), [31:16]=bf16(b)  (RNE)
}

__global__ void zero_sp(float* __restrict__ sp) {
    int i = blockIdx.x * blockDim.x + threadIdx.x;
    ((f32x4*)sp)[i] = (f32x4){0.f, 0.f, 0.f, 0.f};
}

__global__ void finalize(const float* __restrict__ S, const float* __restrict__ P,
                         float* __restrict__ out) {
    int i = blockIdx.x * blockDim.x + threadIdx.x;
    out[i] = P[i] / (S[i] + 1e-16f);
}

// MODE 0: plain-store partials; MODE 1: atomic fallback (part=S, P=P)
template<int MODE>
__global__ __launch_bounds__(NTHREADS, 2) void gemm_fused(
    const float* __restrict__ x, const int* __restrict__ gidx,
    const float* __restrict__ W, const float* __restrict__ bias,
    const float* __restrict__ temp, float* __restrict__ part, float* __restrict__ P,
    int NT)
{
    __shared__ __align__(16) short Alds[2][BUFSH];   // 2 x 68 KB bf16 (padded)
    __shared__ uint4 Mlds[16][2];

    const int t = threadIdx.x;
    const int w = t >> 6;          // wave 0..7: channels [w*32, w*32+32)
    const int l = t & 63;
    const int lrow = l & 15;
    const int lq = l >> 4;
    const int blk = blockIdx.x;

    // ---- prologue meta: wave w computes tiles it = w, w+8 (<=13 tiles/block) ----
#pragma unroll
    for (int k = 0; k < 2; ++k) {
        const int it = w + k * 8;
        const int tile = blk + it * NGRID;
        if (tile < NT) {
            const int sidA = gidx[(size_t)tile * BM + l];
            const int sidB = gidx[(size_t)tile * BM + 64 + l];
            const int s0 = __shfl(sidA, 0);
            const int sL = __shfl(sidB, 63);
            const unsigned long long mA = __ballot(sidA != s0);
            const unsigned long long mB = __ballot(sidB != s0);
            if (l == 0) {
                Mlds[it][0] = make_uint4((unsigned)s0, (unsigned)sL,
                                         (unsigned)mA, (unsigned)(mA >> 32));
                Mlds[it][1] = make_uint4((unsigned)mB, (unsigned)(mB >> 32), 0u, 0u);
            }
        }
    }

    // ---- W fp32 -> bf16 VGPRs: 16 x short8 = 64 VGPRs ----
    short8 bvAll[2][8];
#pragma unroll
    for (int ni = 0; ni < 2; ++ni)
#pragma unroll
        for (int ks = 0; ks < 8; ++ks) {
            const float* wp = W + (size_t)(w * 32 + ni * 16 + lrow) * D_INN + ks * 32 + lq * 8;
            float4 a = ((const float4*)wp)[0];
            float4 b = ((const float4*)wp)[1];
            u32x4 ua;
            ua.x = pk2(a.x, a.y); ua.y = pk2(a.z, a.w);
            ua.z = pk2(b.x, b.y); ua.w = pk2(b.z, b.w);
            bvAll[ni][ks] = __builtin_bit_cast(short8, ua);
        }
    float bb[2], tt[2];
#pragma unroll
    for (int ni = 0; ni < 2; ++ni) {
        bb[ni] = bias[w * 32 + ni * 16 + lrow];
        tt[ni] = temp[w * 32 + ni * 16 + lrow];
    }

    // staging (per half, 64 rows): thread t -> float4 #(r*512+t), r=0..7
    //   row(within half) = r*8+w, col = l*4 -> LDS byte = (half*64 + row)*PSB + l*8
    const int wroff = w * PSB + l * 8;                 // + r*8*PSB + half*64*PSB
    const int rb = lrow * PSB + lq * 16;               // + mi*16*PSB + ks*64

    float4 ra[8], rbuf[8];

#define LOAD8H(dst, tile, half)                                                 \
    {                                                                           \
        const float4* xp = (const float4*)(x + (size_t)(tile) * (BM * D_INN)    \
                                             + (half) * 64 * D_INN) + t;        \
        _Pragma("unroll")                                                       \
        for (int r = 0; r < 8; ++r) dst[r] = xp[r * 512];                       \
    }

#define CVTW(src, bufi, half)                                                   \
    {                                                                           \
        char* wrbase = (char*)&Alds[bufi][0] + (half) * 64 * PSB + wroff;       \
        _Pragma("unroll")                                                       \
        for (int r = 0; r < 8; ++r) {                                           \
            u32x2 p;                                                            \
            p.x = pk2(src[r].x, src[r].y);                                      \
            p.y = pk2(src[r].z, src[r].w);                                      \
            *(u32x2*)(wrbase + r * 8 * PSB) = p;                                \
        }                                                                       \
    }

#define COMPUTE_STORE(bufidx, it, jt)                                           \
    {                                                                           \
        const uint4 mt0 = Mlds[it][0];                                          \
        const uint4 mt1 = Mlds[it][1];                                          \
        f32x4 acc[8][2];                                                        \
        _Pragma("unroll")                                                       \
        for (int i = 0; i < 8; ++i)                                             \
            _Pragma("unroll")                                                   \
            for (int j = 0; j < 2; ++j) acc[i][j] = (f32x4){0.f, 0.f, 0.f, 0.f};\
        const char* lb = (const char*)&Alds[bufidx][0] + rb;                    \
        _Pragma("unroll")                                                       \
        for (int ks = 0; ks < 8; ++ks) {                                        \
            short8 av[8];                                                       \
            _Pragma("unroll")                                                   \
            for (int mi = 0; mi < 8; ++mi)                                      \
                av[mi] = *(const short8*)(lb + mi * 16 * PSB + ks * 64);        \
            _Pragma("unroll")                                                   \
            for (int mi = 0; mi < 8; ++mi)                                      \
                _Pragma("unroll")                                               \
                for (int ni = 0; ni < 2; ++ni)                                  \
                    acc[mi][ni] = __builtin_amdgcn_mfma_f32_16x16x32_bf16(      \
                        av[mi], bvAll[ni][ks], acc[mi][ni], 0, 0, 0);           \
        }                                                                       \
        const int s0 = (int)mt0.x, sL = (int)mt0.y;                             \
        float* pb = part + ((size_t)(jt) << 10);                                \
        unsigned himask = 0;                                                    \
        _Pragma("unroll")                                                       \
        for (int mi = 0; mi < 8; ++mi) {                                        \
            const unsigned mk = (mi < 2) ? mt0.z : (mi < 4) ? mt0.w             \
                              : (mi < 6) ? mt1.x : mt1.y;                       \
            const int base = (mi & 1) * 16 + lq * 4;                            \
            _Pragma("unroll")                                                   \
            for (int j = 0; j < 4; ++j)                                         \
                if ((mk >> (base + j)) & 1) himask |= 1u << (mi * 4 + j);       \
        }                                                                       \
        _Pragma("unroll")                                                       \
        for (int ni = 0; ni < 2; ++ni) {                                        \
            float es0 = 0.f, ps0 = 0.f, es1 = 0.f, ps1 = 0.f;                   \
            _Pragma("unroll")                                                   \
            for (int mi = 0; mi < 8; ++mi)                                      \
                _Pragma("unroll")                                               \
                for (int j = 0; j < 4; ++j) {                                   \
                    float h = fmaxf(acc[mi][ni][j] + bb[ni], 0.f);              \
                    float e = __expf(h * tt[ni]);                               \
                    if ((himask >> (mi * 4 + j)) & 1) { es1 += e; ps1 += h * e; }\
                    else                              { es0 += e; ps0 += h * e; }\
                }                                                               \
            es0 += __shfl_xor(es0, 16); ps0 += __shfl_xor(ps0, 16);             \
            es0 += __shfl_xor(es0, 32); ps0 += __shfl_xor(ps0, 32);             \
            es1 += __shfl_xor(es1, 16); ps1 += __shfl_xor(ps1, 16);             \
            es1 += __shfl_xor(es1, 32); ps1 += __shfl_xor(ps1, 32);             \
            if (l < 16) {                                                       \
                const int ch = w * 32 + ni * 16 + lrow;                         \
                if (MODE == 1) {                                                \
                    atomicAdd(&part[(size_t)s0 * HID + ch], es0);               \
                    atomicAdd(&P[(size_t)s0 * HID + ch], ps0);                  \
                    atomicAdd(&part[(size_t)sL * HID + ch], es1);               \
                    atomicAdd(&P[(size_t)sL * HID + ch], ps1);                  \
                } else {                                                        \
                    f32x4 v; v.x = es0; v.y = ps0; v.z = es1; v.w = ps1;        \
                    *(f32x4*)&pb[4 * ch] = v;                                   \
                }                                                               \
            }                                                                   \
        }                                                                       \
    }

#define FENCE_BARRIER()                                          \
    asm volatile("s_waitcnt lgkmcnt(0)" ::: "memory");           \
    __builtin_amdgcn_s_barrier();                                \
    __builtin_amdgcn_sched_barrier(0);

    // ---- prologue: tile0 both halves -> buf0; tile1 h1 -> rbuf (in flight) ----
    LOAD8H(ra, blk, 0);
    LOAD8H(rbuf, blk, 1);
    __builtin_amdgcn_sched_barrier(0);
    CVTW(ra, 0, 0);
    CVTW(rbuf, 0, 1);
    LOAD8H(rbuf, blk + NGRID, 0);      // blk+NGRID <= 511 < NT=3125 always
    FENCE_BARRIER();                   // publishes buf0 + Mlds

    for (int it = 0;; ++it) {
        const int jt = blk + it * NGRID;
        if (jt >= NT) break;
        const int nxt = jt + NGRID;
        const bool more = nxt < NT;
        if (more) { LOAD8H(ra, nxt, 1); }          // next tile half2
        __builtin_amdgcn_sched_barrier(0);
        COMPUTE_STORE(it & 1, it, jt);
        if (more) {
            CVTW(rbuf, (it + 1) & 1, 0);           // h1: loaded last body (old)
            CVTW(ra, (it + 1) & 1, 1);             // h2: covered by this compute
            if (nxt + NGRID < NT) { LOAD8H(rbuf, nxt + NGRID, 0); }
            FENCE_BARRIER();
        }
    }
#undef LOAD8H
#undef CVTW
#undef COMPUTE_STORE
#undef FENCE_BARRIER
}

// one block per segment; thread = channel; binary-search tile range in sorted gidx
__global__ void reduce_seg(const int* __restrict__ gidx, const float* __restrict__ part,
                           float* __restrict__ out, int N) {
    const int g = blockIdx.x;
    const int ch = threadIdx.x;
    int lo = 0, hi = N;
    while (lo < hi) { int m = (lo + hi) >> 1; if (gidx[m] < g) lo = m + 1; else hi = m; }
    const int r0 = lo;
    hi = N;
    while (lo < hi) { int m = (lo + hi) >> 1; if (gidx[m] < g + 1) lo = m + 1; else hi = m; }
    const int r1 = lo;
    float es = 0.f, ps = 0.f;
    if (r0 < r1) {
        const int b0 = r0 >> 7, b1 = (r1 - 1) >> 7;   // BM = 128
        for (int b = b0; b <= b1; ++b) {
            const f32x4* pb = (const f32x4*)(part + ((size_t)b << 10));
            f32x4 v = pb[ch];
            if (gidx[b << 7] == g) { es += v.x; ps += v.y; }   // tile starts in g
            else                   { es += v.z; ps += v.w; }   // tail rows from prev seg
        }
    }
    out[(size_t)g * HID + ch] = ps / (es + 1e-16f);
}

extern "C" void kernel_launch(void* const* d_in, const int* in_sizes, int n_in,
                              void* d_out, int out_size, void* d_ws, size_t ws_size,
                              hipStream_t stream) {
    const float* x    = (const float*)d_in[0];
    const int*   gidx = (const int*)d_in[1];
    const float* W    = (const float*)d_in[3];
    const float* bias = (const float*)d_in[4];
    const float* temp = (const float*)d_in[5];
    float* out = (float*)d_out;

    const int N = in_sizes[1];        // 400000
    const int B = out_size / HID;     // 1024
    const int NT = N / BM;            // 3125 tiles

    const size_t partFloats = (size_t)NT * 1024;
    const size_t need = partFloats * 4;

    if (ws_size >= need) {
        float* part = (float*)d_ws;
        gemm_fused<0><<<NGRID, NTHREADS, 0, stream>>>(x, gidx, W, bias, temp, part, nullptr, NT);
        reduce_seg<<<B, 256, 0, stream>>>(gidx, part, out, N);
    } else {
        float* S = (float*)d_ws;
        float* P = S + (size_t)B * HID;
        zero_sp<<<(2 * B * HID) / (256 * 4), 256, 0, stream>>>(S);
        gemm_fused<1><<<NGRID, NTHREADS, 0, stream>>>(x, gidx, W, bias, temp, S, P, NT);
        finalize<<<(B * HID) / 256, 256, 0, stream>>>(S, P, out);
    }
}

// Round 21
// 119.919 us; speedup vs baseline: 1.2367x; 1.0829x over previous
//
#include <hip/hip_runtime.h>
#include <hip/hip_bf16.h>

// SoftmaxAggr: h = relu(x @ W^T + b); alpha = segment_softmax(h*t); out = segment_sum(h*alpha)
// |h*t| small -> skip max-subtraction:
//   out[g][c] = sum_{i in g} h*exp(h*t) / (sum_{i in g} exp(h*t) + 1e-16)
// R21 = R17 verbatim (verified 120us best). Structure: bf16 LDS (padded PSB=544),
// reg-staged cvt_pk, compiler-tracked loads, raw-barrier fence, 512thr/8 waves x
// 32ch, BM=64, 1 block/CU, meta in gemm prologue, plain-store partials + reduce.
// Session laws (violations cost 10-28us each, R5/R14/R15/R16/R18/R19/R20):
//  1. Nothing with an in-loop consumer enters the VMEM queue after prefetch loads.
//  2. K-loop lgkmcnt queue stays pure-reads; ds_writes only at the body tail.
//  3. No shfl/bpermute before the K-loop in a scheduling region.
//  4. 512 threads mandatory (W VGPR share); bvAll+ra/rbuf+acc must stay <256 VGPR.
//  5. Ordering: LOAD8 -> sched_barrier -> COMPUTE -> CVTW(tail) -> fence.

typedef __attribute__((ext_vector_type(8))) short short8;
typedef __attribute__((ext_vector_type(4))) float f32x4;
typedef __attribute__((ext_vector_type(4))) unsigned u32x4;
typedef __attribute__((ext_vector_type(2))) unsigned u32x2;

#define D_INN 256
#define HID 256
#define BM 64            // rows per tile = 64 KB fp32 -> 34 KB bf16 (padded) in LDS
#define NGRID 256        // persistent blocks, 1 per CU
#define NTHREADS 512     // 8 waves, each owns 32 channels
#define PSB 544          // padded LDS row stride bytes (272 shorts): conflict-free

__device__ __forceinline__ unsigned pk2(float a, float b) {
    unsigned r;
    asm("v_cvt_pk_bf16_f32 %0, %1, %2" : "=v"(r) : "v"(a), "v"(b));
    return r;   // [15:0]=bf16(a), [31:16]=bf16(b)  (RNE)
}

__global__ void zero_sp(float* __restrict__ sp) {
    int i = blockIdx.x * blockDim.x + threadIdx.x;
    ((f32x4*)sp)[i] = (f32x4){0.f, 0.f, 0.f, 0.f};
}

__global__ void finalize(const float* __restrict__ S, const float* __restrict__ P,
                         float* __restrict__ out) {
    int i = blockIdx.x * blockDim.x + threadIdx.x;
    out[i] = P[i] / (S[i] + 1e-16f);
}

// MODE 0: plain-store partials; MODE 1: atomic fallback (part=S, P=P)
template<int MODE>
__global__ __launch_bounds__(NTHREADS, 2) void gemm_fused(
    const float* __restrict__ x, const int* __restrict__ gidx,
    const float* __restrict__ W, const float* __restrict__ bias,
    const float* __restrict__ temp, float* __restrict__ part, float* __restrict__ P,
    int NT)
{
    __shared__ __align__(16) short Alds[2][BM * (PSB / 2)];   // 2 x 34 KB bf16 (padded)
    __shared__ uint4 Mlds[32];

    const int t = threadIdx.x;
    const int w = t >> 6;          // wave 0..7: channels [w*32, w*32+32)
    const int l = t & 63;
    const int lrow = l & 15;
    const int lq = l >> 4;
    const int blk = blockIdx.x;

    // ---- prologue meta: wave w computes tiles it = w, w+8, w+16, w+24 ----
#pragma unroll
    for (int k = 0; k < 4; ++k) {
        const int it = w + k * 8;
        const int tile = blk + it * NGRID;
        if (tile < NT) {
            const int sid = gidx[(size_t)tile * BM + l];
            const int s0 = __shfl(sid, 0);
            const int s63 = __shfl(sid, 63);
            const unsigned long long m = __ballot(sid != s0);
            if (l == 0)
                Mlds[it] = make_uint4((unsigned)s0, (unsigned)s63,
                                      (unsigned)m, (unsigned)(m >> 32));
        }
    }

    // ---- W fp32 -> bf16 VGPRs: 16 x short8 = 64 VGPRs ----
    short8 bvAll[2][8];
#pragma unroll
    for (int ni = 0; ni < 2; ++ni)
#pragma unroll
        for (int ks = 0; ks < 8; ++ks) {
            const float* wp = W + (size_t)(w * 32 + ni * 16 + lrow) * D_INN + ks * 32 + lq * 8;
            float4 a = ((const float4*)wp)[0];
            float4 b = ((const float4*)wp)[1];
            u32x4 ua;
            ua.x = pk2(a.x, a.y); ua.y = pk2(a.z, a.w);
            ua.z = pk2(b.x, b.y); ua.w = pk2(b.z, b.w);
            bvAll[ni][ks] = __builtin_bit_cast(short8, ua);
        }
    float bb[2], tt[2];
#pragma unroll
    for (int ni = 0; ni < 2; ++ni) {
        bb[ni] = bias[w * 32 + ni * 16 + lrow];
        tt[ni] = temp[w * 32 + ni * 16 + lrow];
    }

    // staging map: thread t handles float4 #(r*512+t), r=0..7 (wave reads 1KB/instr)
    //   elem = (r*512+t)*4 -> row = r*8+w, col = l*4  -> LDS byte = row*PSB + l*8
    char* const wr0 = (char*)&Alds[0][0] + (w * PSB) + l * 8;   // + r*8*PSB
    char* const wr1 = (char*)&Alds[1][0] + (w * PSB) + l * 8;
    // MFMA A-frag read: row = mi*16+lrow, k-bytes = ks*64 + lq*16 (affine, padded)
    const int rb = lrow * PSB + lq * 16;                        // + mi*16*PSB + ks*64

    float4 ra[8], rbuf[8];

#define LOAD8(dst, tile)                                                        \
    {                                                                           \
        const float4* xp = (const float4*)(x + (size_t)(tile) * (BM * D_INN)) + t; \
        _Pragma("unroll")                                                       \
        for (int r = 0; r < 8; ++r) dst[r] = xp[r * 512];                       \
    }

#define CVTW(src, wrbase)                                                       \
    {                                                                           \
        _Pragma("unroll")                                                       \
        for (int r = 0; r < 8; ++r) {                                           \
            u32x2 p;                                                            \
            p.x = pk2(src[r].x, src[r].y);                                      \
            p.y = pk2(src[r].z, src[r].w);                                      \
            *(u32x2*)(wrbase + r * 8 * PSB) = p;                                \
        }                                                                       \
    }

#define COMPUTE_STORE(bufidx, it, jt)                                           \
    {                                                                           \
        const uint4 mt = Mlds[it];                                              \
        f32x4 acc[4][2];                                                        \
        _Pragma("unroll")                                                       \
        for (int i = 0; i < 4; ++i)                                             \
            _Pragma("unroll")                                                   \
            for (int j = 0; j < 2; ++j) acc[i][j] = (f32x4){0.f, 0.f, 0.f, 0.f};\
        const char* lb = (const char*)&Alds[bufidx][0] + rb;                    \
        _Pragma("unroll")                                                       \
        for (int ks = 0; ks < 8; ++ks) {                                        \
            short8 av[4];                                                       \
            _Pragma("unroll")                                                   \
            for (int mi = 0; mi < 4; ++mi)                                      \
                av[mi] = *(const short8*)(lb + mi * 16 * PSB + ks * 64);        \
            _Pragma("unroll")                                                   \
            for (int mi = 0; mi < 4; ++mi)                                      \
                _Pragma("unroll")                                               \
                for (int ni = 0; ni < 2; ++ni)                                  \
                    acc[mi][ni] = __builtin_amdgcn_mfma_f32_16x16x32_bf16(      \
                        av[mi], bvAll[ni][ks], acc[mi][ni], 0, 0, 0);           \
        }                                                                       \
        const int s0 = (int)mt.x, s63 = (int)mt.y;                              \
        float* pb = part + ((size_t)(jt) << 10);                                \
        int himask = 0;                                                         \
        _Pragma("unroll")                                                       \
        for (int mi = 0; mi < 4; ++mi) {                                        \
            const unsigned mk = (mi < 2) ? mt.z : mt.w;                         \
            const int base = (mi & 1) * 16 + lq * 4;                            \
            _Pragma("unroll")                                                   \
            for (int j = 0; j < 4; ++j)                                         \
                if ((mk >> (base + j)) & 1) himask |= 1 << (mi * 4 + j);        \
        }                                                                       \
        _Pragma("unroll")                                                       \
        for (int ni = 0; ni < 2; ++ni) {                                        \
            float es0 = 0.f, ps0 = 0.f, es1 = 0.f, ps1 = 0.f;                   \
            _Pragma("unroll")                                                   \
            for (int mi = 0; mi < 4; ++mi)                                      \
                _Pragma("unroll")                                               \
                for (int j = 0; j < 4; ++j) {                                   \
                    float h = fmaxf(acc[mi][ni][j] + bb[ni], 0.f);              \
                    float e = __expf(h * tt[ni]);                               \
                    if ((himask >> (mi * 4 + j)) & 1) { es1 += e; ps1 += h * e; }\
                    else                              { es0 += e; ps0 += h * e; }\
                }                                                               \
            es0 += __shfl_xor(es0, 16); ps0 += __shfl_xor(ps0, 16);             \
            es0 += __shfl_xor(es0, 32); ps0 += __shfl_xor(ps0, 32);             \
            es1 += __shfl_xor(es1, 16); ps1 += __shfl_xor(ps1, 16);             \
            es1 += __shfl_xor(es1, 32); ps1 += __shfl_xor(ps1, 32);             \
            if (l < 16) {                                                       \
                const int ch = w * 32 + ni * 16 + lrow;                         \
                if (MODE == 1) {                                                \
                    atomicAdd(&part[(size_t)s0 * HID + ch], es0);               \
                    atomicAdd(&P[(size_t)s0 * HID + ch], ps0);                  \
                    atomicAdd(&part[(size_t)s63 * HID + ch], es1);              \
                    atomicAdd(&P[(size_t)s63 * HID + ch], ps1);                 \
                } else {                                                        \
                    f32x4 v; v.x = es0; v.y = ps0; v.z = es1; v.w = ps1;        \
                    *(f32x4*)&pb[4 * ch] = v;                                   \
                }                                                               \
            }                                                                   \
        }                                                                       \
    }

#define FENCE_BARRIER()                                          \
    asm volatile("s_waitcnt lgkmcnt(0)" ::: "memory");           \
    __builtin_amdgcn_s_barrier();                                \
    __builtin_amdgcn_sched_barrier(0);

    // ---- prologue: tile0 -> ra -> LDS0; tile1 -> rbuf (in flight) ----
    LOAD8(ra, blk);
    LOAD8(rbuf, blk + NGRID);          // NT=6250 > 512 always
    __builtin_amdgcn_sched_barrier(0);
    CVTW(ra, wr0);                     // compiler waits ra's loads only
    FENCE_BARRIER();                   // also publishes Mlds (lgkmcnt(0)+barrier)

    for (int it = 0;; it += 2) {
        // ---- even body: compute LDS0; load tile n+2 -> ra; cvt rbuf -> LDS1 ----
        {
            const int n = blk + it * NGRID;
            if (n >= NT) break;
            const int tgt = n + 2 * NGRID;
            if (tgt < NT) LOAD8(ra, tgt);
            __builtin_amdgcn_sched_barrier(0);
            COMPUTE_STORE(0, it, n);
            if (n + NGRID < NT) {
                CVTW(rbuf, wr1);       // compiler-inserted vmcnt: waits rbuf only
                FENCE_BARRIER();
            }
        }
        // ---- odd body: compute LDS1; load tile n+2 -> rbuf; cvt ra -> LDS0 ----
        {
            const int n = blk + (it + 1) * NGRID;
            if (n >= NT) break;
            const int tgt = n + 2 * NGRID;
            if (tgt < NT) LOAD8(rbuf, tgt);
            __builtin_amdgcn_sched_barrier(0);
            COMPUTE_STORE(1, it + 1, n);
            if (n + NGRID < NT) {
                CVTW(ra, wr0);
                FENCE_BARRIER();
            }
        }
    }
#undef LOAD8
#undef CVTW
#undef COMPUTE_STORE
#undef FENCE_BARRIER
}

// one block per segment; thread = channel; binary-search tile range in sorted gidx
__global__ void reduce_seg(const int* __restrict__ gidx, const float* __restrict__ part,
                           float* __restrict__ out, int N) {
    const int g = blockIdx.x;
    const int ch = threadIdx.x;
    int lo = 0, hi = N;
    while (lo < hi) { int m = (lo + hi) >> 1; if (gidx[m] < g) lo = m + 1; else hi = m; }
    const int r0 = lo;
    hi = N;
    while (lo < hi) { int m = (lo + hi) >> 1; if (gidx[m] < g + 1) lo = m + 1; else hi = m; }
    const int r1 = lo;
    float es = 0.f, ps = 0.f;
    if (r0 < r1) {
        const int b0 = r0 >> 6, b1 = (r1 - 1) >> 6;   // BM = 64
        for (int b = b0; b <= b1; ++b) {
            const f32x4* pb = (const f32x4*)(part + ((size_t)b << 10));
            f32x4 v = pb[ch];
            if (gidx[b << 6] == g) { es += v.x; ps += v.y; }   // tile starts in g
            else                   { es += v.z; ps += v.w; }   // tail rows from prev seg
        }
    }
    out[(size_t)g * HID + ch] = ps / (es + 1e-16f);
}

extern "C" void kernel_launch(void* const* d_in, const int* in_sizes, int n_in,
                              void* d_out, int out_size, void* d_ws, size_t ws_size,
                              hipStream_t stream) {
    const float* x    = (const float*)d_in[0];
    const int*   gidx = (const int*)d_in[1];
    const float* W    = (const float*)d_in[3];
    const float* bias = (const float*)d_in[4];
    const float* temp = (const float*)d_in[5];
    float* out = (float*)d_out;

    const int N = in_sizes[1];        // 400000
    const int B = out_size / HID;     // 1024
    const int NT = N / BM;            // 6250 tiles

    const size_t partFloats = (size_t)NT * 1024;
    const size_t need = partFloats * 4;

    if (ws_size >= need) {
        float* part = (float*)d_ws;
        gemm_fused<0><<<NGRID, NTHREADS, 0, stream>>>(x, gidx, W, bias, temp, part, nullptr, NT);
        reduce_seg<<<B, 256, 0, stream>>>(gidx, part, out, N);
    } else {
        float* S = (float*)d_ws;
        float* P = S + (size_t)B * HID;
        zero_sp<<<(2 * B * HID) / (256 * 4), 256, 0, stream>>>(S);
        gemm_fused<1><<<NGRID, NTHREADS, 0, stream>>>(x, gidx, W, bias, temp, S, P, NT);
        finalize<<<(B * HID) / 256, 256, 0, stream>>>(S, P, out);
    }
}